// Round 9
// baseline (243.383 us; speedup 1.0000x reference)
//
#include <hip/hip_runtime.h>
#include <stdint.h>
#include <math.h>

#define BATCH 8
#define NPB   4194304u          // 2048*2048 elements per batch
#define BPB   256               // blocks per batch
#define EPB   16384u            // elements per block (NPB / BPB)

#if defined(__has_builtin)
#if __has_builtin(__builtin_amdgcn_ballot_w64)
#define HAS_BALLOT64 1
#endif
#endif

// native clang ext-vector: accepted by __builtin_nontemporal_{load,store},
// layout-identical to HIP float4 (16B)
typedef float f32x4 __attribute__((ext_vector_type(4)));

// Per-(batch,block) partials. k_main writes EVERY entry each call before
// k_resolve reads them -> immune to workspace poisoning, no memset needed.
struct Ws {
  double   psum[BATCH][BPB];
  uint32_t pcnt[BATCH][BPB];
};

// draw-0 and draw-1 subkeys per batch, computed on host each call
struct Keys {
  uint32_t a0[BATCH], a1[BATCH];   // draw 0
  uint32_t b0[BATCH], b1[BATCH];   // draw 1 (forced-accept fallback)
};

// ---------------- threefry2x32 (bit-exact with JAX) ----------------
__host__ __device__ __forceinline__ uint32_t rotl_h(uint32_t x, int n) {
  return (x << n) | (x >> (32 - n));
}

#ifdef __HIP_DEVICE_COMPILE__
// single v_alignbit_b32: ((x:x) >> (32-n)) == rotl(x,n)
#define ROTL(x, n) __builtin_amdgcn_alignbit((x), (x), 32 - (n))
#else
#define ROTL(x, n) rotl_h((x), (n))
#endif

__host__ __device__ __forceinline__ void tf2x32(uint32_t k0, uint32_t k1,
                                                uint32_t x0, uint32_t x1,
                                                uint32_t& y0, uint32_t& y1) {
  uint32_t k2 = k0 ^ k1 ^ 0x1BD11BDAu;
  x0 += k0; x1 += k1;
#define R4A x0+=x1; x1=ROTL(x1,13); x1^=x0; x0+=x1; x1=ROTL(x1,15); x1^=x0; \
            x0+=x1; x1=ROTL(x1,26); x1^=x0; x0+=x1; x1=ROTL(x1, 6); x1^=x0;
#define R4B x0+=x1; x1=ROTL(x1,17); x1^=x0; x0+=x1; x1=ROTL(x1,29); x1^=x0; \
            x0+=x1; x1=ROTL(x1,16); x1^=x0; x0+=x1; x1=ROTL(x1,24); x1^=x0;
  R4A x0 += k1; x1 += k2 + 1u;
  R4B x0 += k2; x1 += k0 + 2u;
  R4A x0 += k0; x1 += k1 + 3u;
  R4B x0 += k1; x1 += k2 + 4u;
  R4A x0 += k2; x1 += k0 + 5u;
#undef R4A
#undef R4B
  y0 = x0; y1 = x1;
}

// partitionable-mode 32-bit sample for element j: y0 ^ y1 of tf(sub,(0,j))
__device__ __forceinline__ uint32_t tf_bits(uint32_t s0, uint32_t s1, uint32_t j) {
  uint32_t y0, y1;
  tf2x32(s0, s1, 0u, j, y0, y1);
  return y0 ^ y1;
}

// JAX uniform[0,1): bitcast((bits>>9)|0x3f800000) - 1.0
// (bits>>9)|0x3f800000 == alignbit(0x7F, bits, 9) : one VALU op
__device__ __forceinline__ float u01(uint32_t b) {
#ifdef __HIP_DEVICE_COMPILE__
  return __uint_as_float(__builtin_amdgcn_alignbit(0x7Fu, b, 9)) - 1.0f;
#else
  return __uint_as_float((b >> 9) | 0x3f800000u) - 1.0f;
#endif
}

// ---------------- main pass: stats for draw 0 + optimistic mask ----------------
// Ladder (within-session, all absmax=0):
//   unroll1+NT, defused (R3): 92us  | unroll2+NT, defused (R7): ~79us
//   fused w/ __threadfence (R4/R6): 199us  -> never fuse the resolve.
// Mechanism: VMEM store source-VGPRs can't be overwritten until vmcnt retires
// the store; NT stores ack at HBM (~900cy). unroll amortizes the hazard;
// cached stores ack at L2 (~300cy). This round: unroll 4 + cached stores.
// Real VALU duty at 79us is ~43% (2.65e9 lane-ops / 78.6e12/s = 33.7us floor).
__global__ __launch_bounds__(256) void k_main(const float* __restrict__ x,
                                              float* __restrict__ out,
                                              Ws* __restrict__ ws, Keys keys) {
  const int b = blockIdx.y;
  const uint32_t s0 = keys.a0[b], s1 = keys.a1[b];
  const uint32_t base = blockIdx.x * EPB + threadIdx.x * 4u;
  const float* __restrict__ pA = x + (size_t)b * NPB + base;
  float*       __restrict__ qA = out + (size_t)b * NPB + base;

  uint32_t c = 0;          // count: wave-uniform on ballot path
  float    sf = 0.0f;      // per-thread f32 partial sum (<=64 values in [0,1))
  uint32_t j = base;

#pragma unroll 4
  for (int it = 0; it < 8; ++it) {
    f32x4 xa = __builtin_nontemporal_load((const f32x4*)(pA));
    f32x4 xc = __builtin_nontemporal_load((const f32x4*)(pA + 1024));
    f32x4 oa, oc;
#ifdef HAS_BALLOT64
#define CNT(p) c += (uint32_t)__builtin_popcountll(__builtin_amdgcn_ballot_w64(p))
#else
#define CNT(p) c += (uint32_t)(p)
#endif
#define DOPAIR(k, off) {                                                  \
      bool p0 = xa[k] > u01(tf_bits(s0, s1, j + off));                    \
      bool p1 = xc[k] > u01(tf_bits(s0, s1, j + off + 1024u));            \
      oa[k] = p0 ? 1.0f : 0.0f; oc[k] = p1 ? 1.0f : 0.0f;                 \
      CNT(p0); CNT(p1); }
    DOPAIR(0, 0u) DOPAIR(1, 1u) DOPAIR(2, 2u) DOPAIR(3, 3u)
#undef DOPAIR
#undef CNT
    sf += ((xa[0] + xa[1]) + (xa[2] + xa[3])) + ((xc[0] + xc[1]) + (xc[2] + xc[3]));
    *(f32x4*)(qA)        = oa;   // cached store: vmcnt retires at L2, not HBM
    *(f32x4*)(qA + 1024) = oc;
    pA += 2048; qA += 2048; j += 2048u;
  }

  // reduce: sum across wave in f64; count is wave-uniform on the ballot path
  double S = (double)sf;
  for (int off = 32; off > 0; off >>= 1) S += __shfl_down(S, off, 64);
#ifndef HAS_BALLOT64
  for (int off = 32; off > 0; off >>= 1) c += __shfl_down(c, off, 64);
#endif

  __shared__ double   sS[4];
  __shared__ uint32_t sC[4];
  const int lane = threadIdx.x & 63, wave = threadIdx.x >> 6;
  if (lane == 0) { sS[wave] = S; sC[wave] = c; }
  __syncthreads();
  if (threadIdx.x == 0) {
    ws->psum[b][blockIdx.x] = (sS[0] + sS[1]) + (sS[2] + sS[3]);
    ws->pcnt[b][blockIdx.x] = (sC[0] + sC[1]) + (sC[2] + sC[3]);
  }
}

// ---------------- resolve: ONE block per batch decides; rare-path rewrite ----------------
// 8 blocks total: reduce 256 partials, decide, and on the never-path
// (deterministic per input; not taken for the bench input) this single
// block rewrites the whole batch with the draw-1 subkey.
__global__ __launch_bounds__(256) void k_resolve(const float* __restrict__ x,
                                                 float* __restrict__ out,
                                                 Ws* __restrict__ ws, Keys keys) {
  const int b = blockIdx.y;

  double   S = ws->psum[b][threadIdx.x];
  uint32_t c = ws->pcnt[b][threadIdx.x];
  for (int off = 32; off > 0; off >>= 1) {
    c += __shfl_down(c, off, 64);
    S += __shfl_down(S, off, 64);
  }
  __shared__ double   sS[4];
  __shared__ uint32_t sC[4];
  __shared__ int      sAccept;
  const int lane = threadIdx.x & 63, wave = threadIdx.x >> 6;
  if (lane == 0) { sS[wave] = S; sC[wave] = c; }
  __syncthreads();
  if (threadIdx.x == 0) {
    double St = (sS[0] + sS[1]) + (sS[2] + sS[3]);
    uint32_t Ct = (sC[0] + sC[1]) + (sC[2] + sC[3]);
    float target = (float)(St / (double)NPB);
    float thr    = 1e-3f + 1e-5f * fabsf(target);
    float m      = (float)Ct * (1.0f / (float)NPB);
    sAccept = (fabsf(m - target) <= thr) ? 1 : 0;
  }
  __syncthreads();
  if (sAccept) return;

  // never-path: rewrite whole batch with draw-1 subkey (single block; slow but unreachable)
  const uint32_t t0 = keys.b0[b], t1 = keys.b1[b];
  const float* __restrict__ xb = x + (size_t)b * NPB;
  float*       __restrict__ ob = out + (size_t)b * NPB;
#pragma unroll 1
  for (uint32_t jj = threadIdx.x * 4u; jj < NPB; jj += 1024u) {
    float4 v = *(const float4*)(xb + jj);
    float4 o;
    o.x = (v.x > u01(tf_bits(t0, t1, jj + 0u))) ? 1.0f : 0.0f;
    o.y = (v.y > u01(tf_bits(t0, t1, jj + 1u))) ? 1.0f : 0.0f;
    o.z = (v.z > u01(tf_bits(t0, t1, jj + 2u))) ? 1.0f : 0.0f;
    o.w = (v.w > u01(tf_bits(t0, t1, jj + 3u))) ? 1.0f : 0.0f;
    *(float4*)(ob + jj) = o;
  }
}

extern "C" void kernel_launch(void* const* d_in, const int* in_sizes, int n_in,
                              void* d_out, int out_size, void* d_ws, size_t ws_size,
                              hipStream_t stream) {
  const float* x = (const float*)d_in[0];
  float* out = (float*)d_out;
  Ws* ws = (Ws*)d_ws;

  // Host-side key schedule (pure arithmetic — graph-capture safe, same every call).
  // keys[b] = tf((0,42),(0,b)) [fold-in split]; per draw: k' = tf(k,(0,0)), sub = tf(k,(0,1)).
  Keys keys;
  for (int b = 0; b < BATCH; ++b) {
    uint32_t k0, k1, n0, n1, s0, s1;
    tf2x32(0u, 42u, 0u, (uint32_t)b, k0, k1);
    tf2x32(k0, k1, 0u, 1u, s0, s1);      // draw-0 subkey
    keys.a0[b] = s0; keys.a1[b] = s1;
    tf2x32(k0, k1, 0u, 0u, n0, n1);      // advance key
    tf2x32(n0, n1, 0u, 1u, s0, s1);      // draw-1 subkey
    keys.b0[b] = s0; keys.b1[b] = s1;
  }

  hipLaunchKernelGGL(k_main,    dim3(BPB, BATCH), dim3(256), 0, stream, x, out, ws, keys);
  hipLaunchKernelGGL(k_resolve, dim3(1,   BATCH), dim3(256), 0, stream, x, out, ws, keys);
}

// Round 15
// 239.219 us; speedup vs baseline: 1.0174x; 1.0174x over previous
//
#include <hip/hip_runtime.h>
#include <stdint.h>
#include <math.h>

#define BATCH 8
#define NPB   4194304u          // 2048*2048 elements per batch
#define BPB   256               // blocks per batch
#define EPB   16384u            // elements per block (NPB / BPB)

#if defined(__has_builtin)
#if __has_builtin(__builtin_amdgcn_ballot_w64)
#define HAS_BALLOT64 1
#endif
#endif

// native clang ext-vector: accepted by __builtin_nontemporal_{load,store},
// layout-identical to HIP float4 (16B)
typedef float f32x4 __attribute__((ext_vector_type(4)));

// Per-(batch,block) partials. k_main writes EVERY entry each call before
// k_resolve reads them -> immune to workspace poisoning, no memset needed.
struct Ws {
  double   psum[BATCH][BPB];
  uint32_t pcnt[BATCH][BPB];
};

// draw-0 and draw-1 subkeys per batch, computed on host each call
struct Keys {
  uint32_t a0[BATCH], a1[BATCH];   // draw 0
  uint32_t b0[BATCH], b1[BATCH];   // draw 1 (forced-accept fallback)
};

// ---------------- threefry2x32 (bit-exact with JAX) ----------------
__host__ __device__ __forceinline__ uint32_t rotl_h(uint32_t x, int n) {
  return (x << n) | (x >> (32 - n));
}

#ifdef __HIP_DEVICE_COMPILE__
// single v_alignbit_b32: ((x:x) >> (32-n)) == rotl(x,n)
#define ROTL(x, n) __builtin_amdgcn_alignbit((x), (x), 32 - (n))
#else
#define ROTL(x, n) rotl_h((x), (n))
#endif

__host__ __device__ __forceinline__ void tf2x32(uint32_t k0, uint32_t k1,
                                                uint32_t x0, uint32_t x1,
                                                uint32_t& y0, uint32_t& y1) {
  uint32_t k2 = k0 ^ k1 ^ 0x1BD11BDAu;
  x0 += k0; x1 += k1;
#define R4A x0+=x1; x1=ROTL(x1,13); x1^=x0; x0+=x1; x1=ROTL(x1,15); x1^=x0; \
            x0+=x1; x1=ROTL(x1,26); x1^=x0; x0+=x1; x1=ROTL(x1, 6); x1^=x0;
#define R4B x0+=x1; x1=ROTL(x1,17); x1^=x0; x0+=x1; x1=ROTL(x1,29); x1^=x0; \
            x0+=x1; x1=ROTL(x1,16); x1^=x0; x0+=x1; x1=ROTL(x1,24); x1^=x0;
  R4A x0 += k1; x1 += k2 + 1u;
  R4B x0 += k2; x1 += k0 + 2u;
  R4A x0 += k0; x1 += k1 + 3u;
  R4B x0 += k1; x1 += k2 + 4u;
  R4A x0 += k2; x1 += k0 + 5u;
#undef R4A
#undef R4B
  y0 = x0; y1 = x1;
}

// partitionable-mode 32-bit sample for element j: y0 ^ y1 of tf(sub,(0,j))
__device__ __forceinline__ uint32_t tf_bits(uint32_t s0, uint32_t s1, uint32_t j) {
  uint32_t y0, y1;
  tf2x32(s0, s1, 0u, j, y0, y1);
  return y0 ^ y1;
}

// JAX uniform[0,1): bitcast((bits>>9)|0x3f800000) - 1.0
// (bits>>9)|0x3f800000 == alignbit(0x7F, bits, 9) : one VALU op
__device__ __forceinline__ float u01(uint32_t b) {
#ifdef __HIP_DEVICE_COMPILE__
  return __uint_as_float(__builtin_amdgcn_alignbit(0x7Fu, b, 9)) - 1.0f;
#else
  return __uint_as_float((b >> 9) | 0x3f800000u) - 1.0f;
#endif
}

// ---------------- main pass: stats for draw 0 + optimistic mask ----------------
// Ladder (within-session, all absmax=0, traffic constant):
//   unroll1 (R3): 92us | unroll2 (R7): ~79us | unroll4+cached (R9): ~neutral
//   fused w/ __threadfence (R4/R6): 199us -> never fuse the resolve.
// Mechanism now targeted: vmcnt retires VMEM IN ISSUE ORDER. With
// [load,compute,store] per iter, next iter's load-consume waits until the
// PREVIOUS stores retire (~300-900cy ack) every iteration. Fix: issue the
// next iteration's loads BEFORE this iteration's stores (loop-carried
// prefetch) and pin the order with a compiler memory fence so the loads
// can't be sunk to the use site (that sink is what defeated R6's attempt).
// Then the consumed load is always the OLDEST outstanding VMEM op with a
// full iteration (~1250cy) of slack; stores (younger) never gate it.
__global__ __launch_bounds__(256) void k_main(const float* __restrict__ x,
                                              float* __restrict__ out,
                                              Ws* __restrict__ ws, Keys keys) {
  const int b = blockIdx.y;
  const uint32_t s0 = keys.a0[b], s1 = keys.a1[b];
  const uint32_t base = blockIdx.x * EPB + threadIdx.x * 4u;
  const float* __restrict__ pA = x + (size_t)b * NPB + base;
  float*       __restrict__ qA = out + (size_t)b * NPB + base;

  uint32_t c = 0;          // count: wave-uniform on ballot path
  float    sf = 0.0f;      // per-thread f32 partial sum (<=64 values in [0,1))
  uint32_t j = base;

  // prologue: issue iteration 0's loads
  f32x4 xa = __builtin_nontemporal_load((const f32x4*)(pA));
  f32x4 xc = __builtin_nontemporal_load((const f32x4*)(pA + 1024));

#pragma unroll 2
  for (int it = 0; it < 8; ++it) {
    // 1) prefetch next iteration FIRST (program order: before this iter's stores)
    f32x4 na = xa, nc = xc;
    if (it < 7) {
      na = __builtin_nontemporal_load((const f32x4*)(pA + 2048));
      nc = __builtin_nontemporal_load((const f32x4*)(pA + 3072));
    }
    // 2) fence: loads may not sink below, stores may not hoist above.
    //    Keeps the prefetch loads OLDER than this iteration's stores in the
    //    vmcnt in-order retirement stream.
    asm volatile("" ::: "memory");

    // 3) compute on xa/xc (loaded one iteration ago -> vmcnt slack ~1 iter)
    f32x4 oa, oc;
#ifdef HAS_BALLOT64
#define CNT(p) c += (uint32_t)__builtin_popcountll(__builtin_amdgcn_ballot_w64(p))
#else
#define CNT(p) c += (uint32_t)(p)
#endif
#define DOPAIR(k, off) {                                                  \
      bool p0 = xa[k] > u01(tf_bits(s0, s1, j + off));                    \
      bool p1 = xc[k] > u01(tf_bits(s0, s1, j + off + 1024u));            \
      oa[k] = p0 ? 1.0f : 0.0f; oc[k] = p1 ? 1.0f : 0.0f;                 \
      CNT(p0); CNT(p1); }
    DOPAIR(0, 0u) DOPAIR(1, 1u) DOPAIR(2, 2u) DOPAIR(3, 3u)
#undef DOPAIR
#undef CNT
    sf += ((xa[0] + xa[1]) + (xa[2] + xa[3])) + ((xc[0] + xc[1]) + (xc[2] + xc[3]));

    // 4) stores last (youngest VMEM ops -> never gate a later load-consume)
    __builtin_nontemporal_store(oa, (f32x4*)(qA));
    __builtin_nontemporal_store(oc, (f32x4*)(qA + 1024));

    pA += 2048; qA += 2048; j += 2048u;
    xa = na; xc = nc;
  }

  // reduce: sum across wave in f64; count is wave-uniform on the ballot path
  double S = (double)sf;
  for (int off = 32; off > 0; off >>= 1) S += __shfl_down(S, off, 64);
#ifndef HAS_BALLOT64
  for (int off = 32; off > 0; off >>= 1) c += __shfl_down(c, off, 64);
#endif

  __shared__ double   sS[4];
  __shared__ uint32_t sC[4];
  const int lane = threadIdx.x & 63, wave = threadIdx.x >> 6;
  if (lane == 0) { sS[wave] = S; sC[wave] = c; }
  __syncthreads();
  if (threadIdx.x == 0) {
    ws->psum[b][blockIdx.x] = (sS[0] + sS[1]) + (sS[2] + sS[3]);
    ws->pcnt[b][blockIdx.x] = (sC[0] + sC[1]) + (sC[2] + sC[3]);
  }
}

// ---------------- resolve: ONE block per batch decides; rare-path rewrite ----------------
// 8 blocks total: reduce 256 partials, decide, and on the never-path
// (deterministic per input; not taken for the bench input) this single
// block rewrites the whole batch with the draw-1 subkey.
__global__ __launch_bounds__(256) void k_resolve(const float* __restrict__ x,
                                                 float* __restrict__ out,
                                                 Ws* __restrict__ ws, Keys keys) {
  const int b = blockIdx.y;

  double   S = ws->psum[b][threadIdx.x];
  uint32_t c = ws->pcnt[b][threadIdx.x];
  for (int off = 32; off > 0; off >>= 1) {
    c += __shfl_down(c, off, 64);
    S += __shfl_down(S, off, 64);
  }
  __shared__ double   sS[4];
  __shared__ uint32_t sC[4];
  __shared__ int      sAccept;
  const int lane = threadIdx.x & 63, wave = threadIdx.x >> 6;
  if (lane == 0) { sS[wave] = S; sC[wave] = c; }
  __syncthreads();
  if (threadIdx.x == 0) {
    double St = (sS[0] + sS[1]) + (sS[2] + sS[3]);
    uint32_t Ct = (sC[0] + sC[1]) + (sC[2] + sC[3]);
    float target = (float)(St / (double)NPB);
    float thr    = 1e-3f + 1e-5f * fabsf(target);
    float m      = (float)Ct * (1.0f / (float)NPB);
    sAccept = (fabsf(m - target) <= thr) ? 1 : 0;
  }
  __syncthreads();
  if (sAccept) return;

  // never-path: rewrite whole batch with draw-1 subkey (single block; slow but unreachable)
  const uint32_t t0 = keys.b0[b], t1 = keys.b1[b];
  const float* __restrict__ xb = x + (size_t)b * NPB;
  float*       __restrict__ ob = out + (size_t)b * NPB;
#pragma unroll 1
  for (uint32_t jj = threadIdx.x * 4u; jj < NPB; jj += 1024u) {
    float4 v = *(const float4*)(xb + jj);
    float4 o;
    o.x = (v.x > u01(tf_bits(t0, t1, jj + 0u))) ? 1.0f : 0.0f;
    o.y = (v.y > u01(tf_bits(t0, t1, jj + 1u))) ? 1.0f : 0.0f;
    o.z = (v.z > u01(tf_bits(t0, t1, jj + 2u))) ? 1.0f : 0.0f;
    o.w = (v.w > u01(tf_bits(t0, t1, jj + 3u))) ? 1.0f : 0.0f;
    *(float4*)(ob + jj) = o;
  }
}

extern "C" void kernel_launch(void* const* d_in, const int* in_sizes, int n_in,
                              void* d_out, int out_size, void* d_ws, size_t ws_size,
                              hipStream_t stream) {
  const float* x = (const float*)d_in[0];
  float* out = (float*)d_out;
  Ws* ws = (Ws*)d_ws;

  // Host-side key schedule (pure arithmetic — graph-capture safe, same every call).
  // keys[b] = tf((0,42),(0,b)) [fold-in split]; per draw: k' = tf(k,(0,0)), sub = tf(k,(0,1)).
  Keys keys;
  for (int b = 0; b < BATCH; ++b) {
    uint32_t k0, k1, n0, n1, s0, s1;
    tf2x32(0u, 42u, 0u, (uint32_t)b, k0, k1);
    tf2x32(k0, k1, 0u, 1u, s0, s1);      // draw-0 subkey
    keys.a0[b] = s0; keys.a1[b] = s1;
    tf2x32(k0, k1, 0u, 0u, n0, n1);      // advance key
    tf2x32(n0, n1, 0u, 1u, s0, s1);      // draw-1 subkey
    keys.b0[b] = s0; keys.b1[b] = s1;
  }

  hipLaunchKernelGGL(k_main,    dim3(BPB, BATCH), dim3(256), 0, stream, x, out, ws, keys);
  hipLaunchKernelGGL(k_resolve, dim3(1,   BATCH), dim3(256), 0, stream, x, out, ws, keys);
}